// Round 5
// baseline (1194.624 us; speedup 1.0000x reference)
//
#include <hip/hip_runtime.h>
#include <math.h>

// ---------------------------------------------------------------------------
// GCN 3-layer forward. Round 4: bucket-partition CSR build.
// Old build (count -> scan -> scatter -> dinv) paid ~100 MB of HBM write in
// line-churn (random 8B writes + 100k-counter atomics). New build:
//   k_bhist  : LDS histogram over NB=ceil(N/256) buckets (dst>>8)
//   k_bscan  : 1-block exclusive scan -> bucket bases (= CSR segment bases)
//   k_part   : append edges to bucket regions (391 hot cursors; sequential
//              writes per bucket -> ~25 KB live write frontier)
//   k_bucket : block-per-bucket: LDS per-node hist+scan+degw -> rowptr/dinv,
//              then local scatter into final ep (block-contiguous ~32 KB).
// Aggregation/GEMM unchanged from round 3 (row pre-scaling by dinv, bf16
// packed gather rows, wave-owns-16-nodes agg).
// ---------------------------------------------------------------------------

__device__ __forceinline__ float2 bf2_unpack(unsigned u) {
    float2 r;
    r.x = __uint_as_float(u << 16);
    r.y = __uint_as_float(u & 0xffff0000u);
    return r;
}
__device__ __forceinline__ unsigned bf2_pack(float a, float b) {
    unsigned ua = __float_as_uint(a);
    unsigned ub = __float_as_uint(b);
    ua = (ua + 0x7fffu + ((ua >> 16) & 1u)) >> 16;
    ub = (ub + 0x7fffu + ((ub >> 16) & 1u)) >> 16;
    return ua | (ub << 16);
}

// ---------- edge-index dtype detection (int32 vs int64 layout) ----------
__global__ void k_detect(const unsigned* __restrict__ raw, int nsample, int* __restrict__ flag) {
    int i = blockIdx.x * blockDim.x + threadIdx.x;
    if (i < nsample) {
        if (raw[2 * i + 1] != 0u) atomicOr(flag, 1);
    }
}

__device__ __forceinline__ int edge_src(const unsigned* raw, int e, int E, int is64) {
    return is64 ? (int)raw[2 * (size_t)e] : (int)raw[e];
}
__device__ __forceinline__ int edge_dst(const unsigned* raw, int e, int E, int is64) {
    return is64 ? (int)raw[2 * ((size_t)E + e)] : (int)raw[(size_t)E + e];
}

// ---------- bucket histogram (bucket = dst >> 8) ----------
__global__ __launch_bounds__(256) void k_bhist(const unsigned* __restrict__ raw,
                                               int* __restrict__ bhist,
                                               const int* __restrict__ flag, int E, int NB) {
    __shared__ int h[512];
    for (int t = threadIdx.x; t < NB; t += 256) h[t] = 0;
    __syncthreads();
    int is64 = (*flag == 0);
    for (int e = blockIdx.x * 256 + threadIdx.x; e < E; e += gridDim.x * 256) {
        int d = edge_dst(raw, e, E, is64);
        atomicAdd(&h[d >> 8], 1);
    }
    __syncthreads();
    for (int t = threadIdx.x; t < NB; t += 256)
        if (h[t]) atomicAdd(&bhist[t], h[t]);
}

// ---------- exclusive scan over buckets -> bases + cursors ----------
__global__ __launch_bounds__(512) void k_bscan(const int* __restrict__ bhist,
                                               int* __restrict__ bstart,
                                               int* __restrict__ bcur, int NB) {
    __shared__ int s[512];
    int tid = threadIdx.x;
    int v = (tid < NB) ? bhist[tid] : 0;
    s[tid] = v;
    __syncthreads();
    for (int off = 1; off < 512; off <<= 1) {
        int t = (tid >= off) ? s[tid - off] : 0;
        __syncthreads();
        if (tid >= off) s[tid] += t;
        __syncthreads();
    }
    int ex = s[tid] - v;  // exclusive
    if (tid <= NB) {
        int val = (tid < NB) ? ex : s[NB > 0 ? NB - 1 : 0];
        bstart[tid] = val;
        if (tid < NB) bcur[tid] = val;
    }
}

// ---------- partition edges into bucket regions ----------
// payload word0 = src | (dst&255)<<24  (requires N < 2^24; N=100k here)
__global__ __launch_bounds__(256) void k_part(const unsigned* __restrict__ raw,
                                              const float* __restrict__ ew,
                                              int* __restrict__ bcur, int2* __restrict__ staging,
                                              const int* __restrict__ flag, int E) {
    int is64 = (*flag == 0);
    for (int e = blockIdx.x * 256 + threadIdx.x; e < E; e += gridDim.x * 256) {
        int s = edge_src(raw, e, E, is64);
        int d = edge_dst(raw, e, E, is64);
        float w = ew[e];
        int pos = atomicAdd(&bcur[d >> 8], 1);
        staging[pos] = make_int2(s | ((d & 255) << 24), __float_as_int(w));
    }
}

// ---------- per-bucket finalize: rowptr, dinv, local scatter -> ep ----------
__global__ __launch_bounds__(256) void k_bucket(const int* __restrict__ bstart,
                                                const int2* __restrict__ staging,
                                                int* __restrict__ rowptr, float* __restrict__ dinv,
                                                int2* __restrict__ ep, int N, int NB) {
    __shared__ int cnt[256];
    __shared__ float dw[256];
    __shared__ int sc[256];
    __shared__ int cur[256];

    const int b = blockIdx.x;
    const int t = threadIdx.x;
    const int n0 = b << 8;
    const int nn = (N - n0 < 256) ? (N - n0) : 256;
    const int es = bstart[b], ee = bstart[b + 1];

    cnt[t] = 0;
    dw[t] = 0.f;
    __syncthreads();

    // phase 1: per-node histogram + weighted degree
    for (int j = es + t; j < ee; j += 256) {
        int2 p = staging[j];
        int dl = ((unsigned)p.x) >> 24;
        atomicAdd(&cnt[dl], 1);
        atomicAdd(&dw[dl], __int_as_float(p.y));
    }
    __syncthreads();

    // phase 2: inclusive scan of cnt -> sc
    int v = cnt[t];
    sc[t] = v;
    __syncthreads();
    for (int off = 1; off < 256; off <<= 1) {
        int tv = (t >= off) ? sc[t - off] : 0;
        __syncthreads();
        if (t >= off) sc[t] += tv;
        __syncthreads();
    }
    int exoff = sc[t] - v;  // exclusive offset within bucket
    cur[t] = es + exoff;
    if (t < nn) {
        rowptr[n0 + t] = es + exoff;
        dinv[n0 + t] = rsqrtf(dw[t] + 1.0f);  // deg includes self-loop 1.0
    }
    if (t == 0) rowptr[(n0 + 256 < N) ? (n0 + 256) : N] = ee;
    __syncthreads();

    // phase 3: local scatter into final CSR slots (block-contiguous region)
    for (int j = es + t; j < ee; j += 256) {
        int2 p = staging[j];
        int dl = ((unsigned)p.x) >> 24;
        int pos = atomicAdd(&cur[dl], 1);
        ep[pos] = make_int2(p.x & 0x00ffffff, p.y);
    }
}

// ---------- fp32 GEMM: Yp = pack_bf162( dinv[r] * act(X)[N,128] @ W ) ----------
template <int DOUT, int KC, bool BN>
__global__ __launch_bounds__(256) void k_gemm(
    const float* __restrict__ X, const float* __restrict__ W,
    const float* __restrict__ scale, const float* __restrict__ shift,
    const float* __restrict__ dscale, unsigned* __restrict__ Y, int N)
{
    constexpr int NCH = 128 / KC;
    constexpr int NDW = DOUT / 2;
    __shared__ __align__(16) float Wl[KC * DOUT];
    __shared__ __align__(16) float Xs[4][8 * 128];
    __shared__ float sc_l[128], sh_l[128];

    const int tid = threadIdx.x;
    const int wave = tid >> 6, lane = tid & 63;
    if (BN) {
        if (tid < 128) { sc_l[tid] = scale[tid]; sh_l[tid] = shift[tid]; }
    }
    __syncthreads();

    const int srow = lane >> 3;
    const int skk = (lane & 7) * 16;

    for (int base = blockIdx.x * 32; base < N; base += gridDim.x * 32) {
        {
            int r = base + wave * 8 + srow;
            float4 v[4];
            if (r < N) {
                const float4* p = (const float4*)(X + (size_t)r * 128 + skk);
                v[0] = p[0]; v[1] = p[1]; v[2] = p[2]; v[3] = p[3];
            } else {
                v[0] = v[1] = v[2] = v[3] = make_float4(0.f, 0.f, 0.f, 0.f);
            }
            if (BN) {
                float* vf = (float*)v;
#pragma unroll
                for (int j = 0; j < 16; j++)
                    vf[j] = fmaxf(vf[j] * sc_l[skk + j] + sh_l[skk + j], 0.f);
            }
            float4* q = (float4*)&Xs[wave][srow * 128 + skk];
            q[0] = v[0]; q[1] = v[1]; q[2] = v[2]; q[3] = v[3];
        }

        float acc0[8], acc1[8];
#pragma unroll
        for (int r = 0; r < 8; r++) { acc0[r] = 0.f; acc1[r] = 0.f; }

        for (int ch = 0; ch < NCH; ++ch) {
            __syncthreads();
            for (int idx = tid; idx < KC * DOUT / 4; idx += 256)
                ((float4*)Wl)[idx] = ((const float4*)(W + (size_t)ch * KC * DOUT))[idx];
            __syncthreads();

            for (int k = 0; k < KC; k += 4) {
                float4 a[8];
#pragma unroll
                for (int r = 0; r < 8; r++)
                    a[r] = *(const float4*)&Xs[wave][r * 128 + ch * KC + k];
#pragma unroll
                for (int kk = 0; kk < 4; kk++) {
                    float2 wv = make_float2(0.f, 0.f);
                    if (lane < NDW)
                        wv = *(const float2*)&Wl[(k + kk) * DOUT + 2 * lane];
#pragma unroll
                    for (int r = 0; r < 8; r++) {
                        float av = ((const float*)&a[r])[kk];
                        acc0[r] += av * wv.x;
                        acc1[r] += av * wv.y;
                    }
                }
            }
        }

#pragma unroll
        for (int r = 0; r < 8; r++) {
            int row = base + wave * 8 + r;
            if (row < N && lane < NDW) {
                float rs = dscale[row];
                Y[(size_t)row * NDW + lane] = bf2_pack(acc0[r] * rs, acc1[r] * rs);
            }
        }
    }
}

// ---------- aggregation (128-wide, bf16 gather) + bias + BN partial sums ----------
__global__ __launch_bounds__(256) void k_agg128(
    const unsigned* __restrict__ xw, const int* __restrict__ rowptr,
    const int2* __restrict__ ep, const float* __restrict__ dinv,
    const float* __restrict__ bias, float* __restrict__ h,
    float* __restrict__ bn_sum, float* __restrict__ bn_sq, int N)
{
    __shared__ float redS[512], redQ[512];
    const int lane = threadIdx.x & 63;
    const int wave = threadIdx.x >> 6;
    const int base = blockIdx.x * 64 + wave * 16;
    const float b0 = bias[2 * lane], b1 = bias[2 * lane + 1];
    float s0 = 0.f, s1 = 0.f, q0 = 0.f, q1 = 0.f;

    const int nmax = (N - base < 16) ? (N - base) : 16;
    for (int n = 0; n < nmax; n++) {
        const int i = base + n;
        const int rs = rowptr[i], re = rowptr[i + 1];
        const float di = dinv[i];
        float2 sv = bf2_unpack(xw[(size_t)i * 64 + lane]);
        float acc0 = sv.x, acc1 = sv.y;  // self-loop message xw'[i]
        int j = rs;
        for (; j + 4 <= re; j += 4) {
            int2 e0 = ep[j], e1 = ep[j + 1], e2 = ep[j + 2], e3 = ep[j + 3];
            unsigned v0 = xw[(size_t)e0.x * 64 + lane];
            unsigned v1 = xw[(size_t)e1.x * 64 + lane];
            unsigned v2 = xw[(size_t)e2.x * 64 + lane];
            unsigned v3 = xw[(size_t)e3.x * 64 + lane];
            float c0 = __int_as_float(e0.y), c1 = __int_as_float(e1.y);
            float c2 = __int_as_float(e2.y), c3 = __int_as_float(e3.y);
            float2 f0 = bf2_unpack(v0), f1 = bf2_unpack(v1);
            float2 f2 = bf2_unpack(v2), f3 = bf2_unpack(v3);
            acc0 += c0 * f0.x + c1 * f1.x + c2 * f2.x + c3 * f3.x;
            acc1 += c0 * f0.y + c1 * f1.y + c2 * f2.y + c3 * f3.y;
        }
        for (; j < re; j++) {
            int2 e = ep[j];
            float c = __int_as_float(e.y);
            float2 f = bf2_unpack(xw[(size_t)e.x * 64 + lane]);
            acc0 += c * f.x;
            acc1 += c * f.y;
        }
        acc0 = acc0 * di + b0;
        acc1 = acc1 * di + b1;
        *(float2*)&h[(size_t)i * 128 + 2 * lane] = make_float2(acc0, acc1);
        s0 += acc0; s1 += acc1; q0 += acc0 * acc0; q1 += acc1 * acc1;
    }

    redS[wave * 128 + 2 * lane] = s0;
    redS[wave * 128 + 2 * lane + 1] = s1;
    redQ[wave * 128 + 2 * lane] = q0;
    redQ[wave * 128 + 2 * lane + 1] = q1;
    __syncthreads();
    if (threadIdx.x < 128) {
        int f = threadIdx.x;
        float ts = redS[f] + redS[128 + f] + redS[256 + f] + redS[384 + f];
        float tq = redQ[f] + redQ[128 + f] + redQ[256 + f] + redQ[384 + f];
        atomicAdd(&bn_sum[f], ts);
        atomicAdd(&bn_sq[f], tq);
    }
}

// ---------- BN finalize ----------
__global__ void k_bnfin(const float* __restrict__ bn_sum, const float* __restrict__ bn_sq,
                        const float* __restrict__ gamma, const float* __restrict__ beta,
                        float* __restrict__ scale, float* __restrict__ shift, int N) {
    int f = threadIdx.x;
    float inv = 1.0f / (float)N;
    float m = bn_sum[f] * inv;
    float v = bn_sq[f] * inv - m * m;
    float sc = gamma[f] * rsqrtf(v + 1e-5f);
    scale[f] = sc;
    shift[f] = beta[f] - m * sc;
}

// ---------- aggregation (40-wide, bf16 gather) + bias + log_softmax ----------
__global__ __launch_bounds__(256) void k_agg40(
    const unsigned* __restrict__ xw, const int* __restrict__ rowptr,
    const int2* __restrict__ ep, const float* __restrict__ dinv,
    const float* __restrict__ bias, float* __restrict__ out, int N)
{
    const int lane = threadIdx.x & 63;
    const int wave = threadIdx.x >> 6;
    const int half = lane >> 5;
    const int col = lane & 31;
    const bool act = col < 20;
    const int base = blockIdx.x * 64 + wave * 16;
    if (base >= N) return;
    const int cc = act ? col : 0;
    const float b0 = act ? bias[2 * col] : 0.f;
    const float b1 = act ? bias[2 * col + 1] : 0.f;

    for (int n = 0; n < 16; n += 2) {
        const int i = base + n + half;
        const bool valid = i < N;
        const int ic = valid ? i : 0;
        const int rs = rowptr[ic];
        int re = rowptr[ic + 1];
        re = valid ? re : rs;
        const float di = dinv[ic];
        float2 sv = bf2_unpack(xw[(size_t)ic * 20 + cc]);
        float acc0 = sv.x, acc1 = sv.y;  // self-loop message
        int j = rs;
        for (; j + 4 <= re; j += 4) {
            int2 e0 = ep[j], e1 = ep[j + 1], e2 = ep[j + 2], e3 = ep[j + 3];
            unsigned v0 = xw[(size_t)e0.x * 20 + cc];
            unsigned v1 = xw[(size_t)e1.x * 20 + cc];
            unsigned v2 = xw[(size_t)e2.x * 20 + cc];
            unsigned v3 = xw[(size_t)e3.x * 20 + cc];
            float c0 = __int_as_float(e0.y), c1 = __int_as_float(e1.y);
            float c2 = __int_as_float(e2.y), c3 = __int_as_float(e3.y);
            float2 f0 = bf2_unpack(v0), f1 = bf2_unpack(v1);
            float2 f2 = bf2_unpack(v2), f3 = bf2_unpack(v3);
            acc0 += c0 * f0.x + c1 * f1.x + c2 * f2.x + c3 * f3.x;
            acc1 += c0 * f0.y + c1 * f1.y + c2 * f2.y + c3 * f3.y;
        }
        for (; j < re; j++) {
            int2 e = ep[j];
            float c = __int_as_float(e.y);
            float2 f = bf2_unpack(xw[(size_t)e.x * 20 + cc]);
            acc0 += c * f.x;
            acc1 += c * f.y;
        }
        acc0 = acc0 * di + b0;
        acc1 = acc1 * di + b1;

        float m = act ? fmaxf(acc0, acc1) : -1e30f;
#pragma unroll
        for (int off = 16; off; off >>= 1) m = fmaxf(m, __shfl_xor(m, off));
        float ex = act ? (expf(acc0 - m) + expf(acc1 - m)) : 0.f;
#pragma unroll
        for (int off = 16; off; off >>= 1) ex += __shfl_xor(ex, off);
        float ls = logf(ex);
        if (act && valid)
            *(float2*)&out[(size_t)i * 40 + 2 * col] = make_float2(acc0 - m - ls, acc1 - m - ls);
    }
}

// ---------------------------------------------------------------------------
extern "C" void kernel_launch(void* const* d_in, const int* in_sizes, int n_in,
                              void* d_out, int out_size, void* d_ws, size_t ws_size,
                              hipStream_t stream) {
    const float* x   = (const float*)d_in[0];
    const unsigned* ei = (const unsigned*)d_in[1];
    const float* ew  = (const float*)d_in[2];
    const float* W0  = (const float*)d_in[3];
    const float* b0  = (const float*)d_in[4];
    const float* g0  = (const float*)d_in[5];
    const float* be0 = (const float*)d_in[6];
    const float* W1  = (const float*)d_in[7];
    const float* b1  = (const float*)d_in[8];
    const float* g1  = (const float*)d_in[9];
    const float* be1 = (const float*)d_in[10];
    const float* W2  = (const float*)d_in[11];
    const float* b2  = (const float*)d_in[12];

    const int N = in_sizes[0] / 128;
    const int E = in_sizes[2];
    if (N <= 0 || E <= 0) return;
    const int NB = (N + 255) >> 8;  // nodes-per-bucket = 256; requires NB <= 512

    char* ws = (char*)d_ws;
    size_t off = 0;
    auto carve = [&](size_t bytes) {
        char* p = ws + off;
        off += (bytes + 511) & ~((size_t)511);
        return p;
    };
    float*    F       = (float*)carve((size_t)N * 128 * 4);    // fp32 h buffer
    unsigned* P       = (unsigned*)carve((size_t)N * 64 * 4);  // packed bf162 xw'
    int2*     ep      = (int2*)carve((size_t)E * 8);           // final CSR (src, ew)
    int2*     staging = (int2*)carve((size_t)E * 8);           // bucket-ordered edges
    int*      rowptr  = (int*)carve((size_t)(N + 1) * 4);
    float*    dinv    = (float*)carve((size_t)N * 4);
    int*      bhist   = (int*)carve(513 * 4);
    int*      bstart  = (int*)carve(513 * 4);
    int*      bcur    = (int*)carve(513 * 4);
    float*    bn      = (float*)carve(512 * 4);
    int*      flag    = (int*)carve(64);

    hipMemsetAsync(bhist, 0, 513 * 4, stream);
    hipMemsetAsync(flag, 0, 4, stream);

    int nsample = E < 4096 ? E : 4096;
    k_detect<<<(nsample + 255) / 256, 256, 0, stream>>>(ei, nsample, flag);
    k_bhist<<<1024, 256, 0, stream>>>(ei, bhist, flag, E, NB);
    k_bscan<<<1, 512, 0, stream>>>(bhist, bstart, bcur, NB);
    k_part<<<2048, 256, 0, stream>>>(ei, ew, bcur, staging, flag, E);
    k_bucket<<<NB, 256, 0, stream>>>(bstart, staging, rowptr, dinv, ep, N, NB);

    const int gemm_grid = 768;
    const int agg_grid = (N + 63) / 64;

    // ---- layer 0 ----
    k_gemm<128, 64, false><<<gemm_grid, 256, 0, stream>>>(x, W0, nullptr, nullptr, dinv, P, N);
    hipMemsetAsync(bn, 0, 1024, stream);
    k_agg128<<<agg_grid, 256, 0, stream>>>(P, rowptr, ep, dinv, b0, F, bn, bn + 128, N);
    k_bnfin<<<1, 128, 0, stream>>>(bn, bn + 128, g0, be0, bn + 256, bn + 384, N);

    // ---- layer 1 ----
    k_gemm<128, 64, true><<<gemm_grid, 256, 0, stream>>>(F, W1, bn + 256, bn + 384, dinv, P, N);
    hipMemsetAsync(bn, 0, 1024, stream);
    k_agg128<<<agg_grid, 256, 0, stream>>>(P, rowptr, ep, dinv, b1, F, bn, bn + 128, N);
    k_bnfin<<<1, 128, 0, stream>>>(bn, bn + 128, g1, be1, bn + 256, bn + 384, N);

    // ---- layer 2 ----
    k_gemm<40, 128, true><<<gemm_grid, 256, 0, stream>>>(F, W2, bn + 256, bn + 384, dinv, P, N);
    k_agg40<<<agg_grid, 256, 0, stream>>>(P, rowptr, ep, dinv, b2, (float*)d_out, N);
}

// Round 6
// 653.294 us; speedup vs baseline: 1.8286x; 1.8286x over previous
//
#include <hip/hip_runtime.h>
#include <math.h>

// ---------------------------------------------------------------------------
// GCN 3-layer forward. Round 5: bucket-partition CSR build with CHUNK-BATCHED
// cursor claims. Round-4 failure: per-edge global atomics onto 391 cursors
// serialized at ~136 ns/atomic (4092-deep same-address chains) -> 557 us.
// Fix: per-chunk (8192-edge) LDS histograms stored to chist[][]; k_part
// claims each bucket range with ONE atomic per (chunk,bucket) (~196 per
// address over the whole kernel), then scatters via LDS cursors into
// exclusively-owned contiguous staging ranges.
//   k_bhist  : chunk LDS hist -> chist[c][b] + merged bucket totals
//   k_bscan  : 1-block exclusive scan -> bucket bases
//   k_part   : claim ranges from chist, scatter edges (LDS cursors)
//   k_bucket : block-per-bucket: per-node hist+scan+degw -> rowptr/dinv,
//              local scatter into final ep (block-contiguous region).
// GEMM/aggregation unchanged from round 3 (dinv row pre-scaling, bf16-packed
// gather rows, wave-owns-16-nodes aggregation).
// ---------------------------------------------------------------------------

#define CHUNK 8192  // edges per partition chunk (256 thr x 32)

__device__ __forceinline__ float2 bf2_unpack(unsigned u) {
    float2 r;
    r.x = __uint_as_float(u << 16);
    r.y = __uint_as_float(u & 0xffff0000u);
    return r;
}
__device__ __forceinline__ unsigned bf2_pack(float a, float b) {
    unsigned ua = __float_as_uint(a);
    unsigned ub = __float_as_uint(b);
    ua = (ua + 0x7fffu + ((ua >> 16) & 1u)) >> 16;
    ub = (ub + 0x7fffu + ((ub >> 16) & 1u)) >> 16;
    return ua | (ub << 16);
}

// ---------- edge-index dtype detection (int32 vs int64 layout) ----------
__global__ void k_detect(const unsigned* __restrict__ raw, int nsample, int* __restrict__ flag) {
    int i = blockIdx.x * blockDim.x + threadIdx.x;
    if (i < nsample) {
        if (raw[2 * i + 1] != 0u) atomicOr(flag, 1);
    }
}

__device__ __forceinline__ int edge_src(const unsigned* raw, int e, int E, int is64) {
    return is64 ? (int)raw[2 * (size_t)e] : (int)raw[e];
}
__device__ __forceinline__ int edge_dst(const unsigned* raw, int e, int E, int is64) {
    return is64 ? (int)raw[2 * ((size_t)E + e)] : (int)raw[(size_t)E + e];
}

// ---------- per-chunk bucket histograms + merged totals ----------
__global__ __launch_bounds__(256) void k_bhist(const unsigned* __restrict__ raw,
                                               int* __restrict__ bhist, int* __restrict__ chist,
                                               const int* __restrict__ flag,
                                               int E, int NB, int nchunks) {
    __shared__ int h[512];
    int is64 = (*flag == 0);
    for (int c = blockIdx.x; c < nchunks; c += gridDim.x) {
        for (int t = threadIdx.x; t < 512; t += 256) h[t] = 0;
        __syncthreads();
        int base = c * CHUNK;
        int end = (base + CHUNK < E) ? base + CHUNK : E;
        for (int e = base + threadIdx.x; e < end; e += 256) {
            int d = edge_dst(raw, e, E, is64);
            atomicAdd(&h[d >> 8], 1);
        }
        __syncthreads();
        for (int t = threadIdx.x; t < NB; t += 256) {
            int v = h[t];
            chist[(size_t)c * 512 + t] = v;
            if (v) atomicAdd(&bhist[t], v);
        }
        __syncthreads();
    }
}

// ---------- exclusive scan over buckets -> bases + cursors ----------
__global__ __launch_bounds__(512) void k_bscan(const int* __restrict__ bhist,
                                               int* __restrict__ bstart,
                                               int* __restrict__ bcur, int NB) {
    __shared__ int s[512];
    int tid = threadIdx.x;
    int v = (tid < NB) ? bhist[tid] : 0;
    s[tid] = v;
    __syncthreads();
    for (int off = 1; off < 512; off <<= 1) {
        int t = (tid >= off) ? s[tid - off] : 0;
        __syncthreads();
        if (tid >= off) s[tid] += t;
        __syncthreads();
    }
    int ex = s[tid] - v;  // exclusive
    if (tid <= NB) {
        int val = (tid < NB) ? ex : s[NB > 0 ? NB - 1 : 0];
        bstart[tid] = val;
        if (tid < NB) bcur[tid] = val;
    }
}

// ---------- partition: chunk-batched claims, LDS-cursor scatter ----------
// payload word0 = src | (dst&255)<<24  (requires N < 2^24; N=100k here)
__global__ __launch_bounds__(256) void k_part(const unsigned* __restrict__ raw,
                                              const float* __restrict__ ew,
                                              const int* __restrict__ chist,
                                              int* __restrict__ bcur, int2* __restrict__ staging,
                                              const int* __restrict__ flag,
                                              int E, int NB, int nchunks) {
    __shared__ int cur[512];
    int is64 = (*flag == 0);
    for (int c = blockIdx.x; c < nchunks; c += gridDim.x) {
        // claim this chunk's range in each bucket (one atomic per nonzero bucket)
        for (int t = threadIdx.x; t < NB; t += 256) {
            int v = chist[(size_t)c * 512 + t];
            cur[t] = v ? atomicAdd(&bcur[t], v) : 0;
        }
        __syncthreads();
        int base = c * CHUNK;
        int end = (base + CHUNK < E) ? base + CHUNK : E;
        for (int e = base + threadIdx.x; e < end; e += 256) {
            int s = edge_src(raw, e, E, is64);
            int d = edge_dst(raw, e, E, is64);
            float w = ew[e];
            int pos = atomicAdd(&cur[d >> 8], 1);  // LDS atomic
            staging[pos] = make_int2(s | ((d & 255) << 24), __float_as_int(w));
        }
        __syncthreads();
    }
}

// ---------- per-bucket finalize: rowptr, dinv, local scatter -> ep ----------
__global__ __launch_bounds__(256) void k_bucket(const int* __restrict__ bstart,
                                                const int2* __restrict__ staging,
                                                int* __restrict__ rowptr, float* __restrict__ dinv,
                                                int2* __restrict__ ep, int N, int NB) {
    __shared__ int cnt[256];
    __shared__ float dw[256];
    __shared__ int sc[256];
    __shared__ int cur[256];

    const int b = blockIdx.x;
    const int t = threadIdx.x;
    const int n0 = b << 8;
    const int nn = (N - n0 < 256) ? (N - n0) : 256;
    const int es = bstart[b], ee = bstart[b + 1];

    cnt[t] = 0;
    dw[t] = 0.f;
    __syncthreads();

    // phase 1: per-node histogram + weighted degree
    for (int j = es + t; j < ee; j += 256) {
        int2 p = staging[j];
        int dl = ((unsigned)p.x) >> 24;
        atomicAdd(&cnt[dl], 1);
        atomicAdd(&dw[dl], __int_as_float(p.y));
    }
    __syncthreads();

    // phase 2: inclusive scan of cnt -> sc
    int v = cnt[t];
    sc[t] = v;
    __syncthreads();
    for (int off = 1; off < 256; off <<= 1) {
        int tv = (t >= off) ? sc[t - off] : 0;
        __syncthreads();
        if (t >= off) sc[t] += tv;
        __syncthreads();
    }
    int exoff = sc[t] - v;  // exclusive offset within bucket
    cur[t] = es + exoff;
    if (t < nn) {
        rowptr[n0 + t] = es + exoff;
        dinv[n0 + t] = rsqrtf(dw[t] + 1.0f);  // deg includes self-loop 1.0
    }
    if (t == 0) rowptr[(n0 + 256 < N) ? (n0 + 256) : N] = ee;
    __syncthreads();

    // phase 3: local scatter into final CSR slots (block-contiguous region)
    for (int j = es + t; j < ee; j += 256) {
        int2 p = staging[j];
        int dl = ((unsigned)p.x) >> 24;
        int pos = atomicAdd(&cur[dl], 1);
        ep[pos] = make_int2(p.x & 0x00ffffff, p.y);
    }
}

// ---------- fp32 GEMM: Yp = pack_bf162( dinv[r] * act(X)[N,128] @ W ) ----------
template <int DOUT, int KC, bool BN>
__global__ __launch_bounds__(256) void k_gemm(
    const float* __restrict__ X, const float* __restrict__ W,
    const float* __restrict__ scale, const float* __restrict__ shift,
    const float* __restrict__ dscale, unsigned* __restrict__ Y, int N)
{
    constexpr int NCH = 128 / KC;
    constexpr int NDW = DOUT / 2;
    __shared__ __align__(16) float Wl[KC * DOUT];
    __shared__ __align__(16) float Xs[4][8 * 128];
    __shared__ float sc_l[128], sh_l[128];

    const int tid = threadIdx.x;
    const int wave = tid >> 6, lane = tid & 63;
    if (BN) {
        if (tid < 128) { sc_l[tid] = scale[tid]; sh_l[tid] = shift[tid]; }
    }
    __syncthreads();

    const int srow = lane >> 3;
    const int skk = (lane & 7) * 16;

    for (int base = blockIdx.x * 32; base < N; base += gridDim.x * 32) {
        {
            int r = base + wave * 8 + srow;
            float4 v[4];
            if (r < N) {
                const float4* p = (const float4*)(X + (size_t)r * 128 + skk);
                v[0] = p[0]; v[1] = p[1]; v[2] = p[2]; v[3] = p[3];
            } else {
                v[0] = v[1] = v[2] = v[3] = make_float4(0.f, 0.f, 0.f, 0.f);
            }
            if (BN) {
                float* vf = (float*)v;
#pragma unroll
                for (int j = 0; j < 16; j++)
                    vf[j] = fmaxf(vf[j] * sc_l[skk + j] + sh_l[skk + j], 0.f);
            }
            float4* q = (float4*)&Xs[wave][srow * 128 + skk];
            q[0] = v[0]; q[1] = v[1]; q[2] = v[2]; q[3] = v[3];
        }

        float acc0[8], acc1[8];
#pragma unroll
        for (int r = 0; r < 8; r++) { acc0[r] = 0.f; acc1[r] = 0.f; }

        for (int ch = 0; ch < NCH; ++ch) {
            __syncthreads();
            for (int idx = tid; idx < KC * DOUT / 4; idx += 256)
                ((float4*)Wl)[idx] = ((const float4*)(W + (size_t)ch * KC * DOUT))[idx];
            __syncthreads();

            for (int k = 0; k < KC; k += 4) {
                float4 a[8];
#pragma unroll
                for (int r = 0; r < 8; r++)
                    a[r] = *(const float4*)&Xs[wave][r * 128 + ch * KC + k];
#pragma unroll
                for (int kk = 0; kk < 4; kk++) {
                    float2 wv = make_float2(0.f, 0.f);
                    if (lane < NDW)
                        wv = *(const float2*)&Wl[(k + kk) * DOUT + 2 * lane];
#pragma unroll
                    for (int r = 0; r < 8; r++) {
                        float av = ((const float*)&a[r])[kk];
                        acc0[r] += av * wv.x;
                        acc1[r] += av * wv.y;
                    }
                }
            }
        }

#pragma unroll
        for (int r = 0; r < 8; r++) {
            int row = base + wave * 8 + r;
            if (row < N && lane < NDW) {
                float rs = dscale[row];
                Y[(size_t)row * NDW + lane] = bf2_pack(acc0[r] * rs, acc1[r] * rs);
            }
        }
    }
}

// ---------- aggregation (128-wide, bf16 gather) + bias + BN partial sums ----------
__global__ __launch_bounds__(256) void k_agg128(
    const unsigned* __restrict__ xw, const int* __restrict__ rowptr,
    const int2* __restrict__ ep, const float* __restrict__ dinv,
    const float* __restrict__ bias, float* __restrict__ h,
    float* __restrict__ bn_sum, float* __restrict__ bn_sq, int N)
{
    __shared__ float redS[512], redQ[512];
    const int lane = threadIdx.x & 63;
    const int wave = threadIdx.x >> 6;
    const int base = blockIdx.x * 64 + wave * 16;
    const float b0 = bias[2 * lane], b1 = bias[2 * lane + 1];
    float s0 = 0.f, s1 = 0.f, q0 = 0.f, q1 = 0.f;

    const int nmax = (N - base < 16) ? (N - base) : 16;
    for (int n = 0; n < nmax; n++) {
        const int i = base + n;
        const int rs = rowptr[i], re = rowptr[i + 1];
        const float di = dinv[i];
        float2 sv = bf2_unpack(xw[(size_t)i * 64 + lane]);
        float acc0 = sv.x, acc1 = sv.y;  // self-loop message xw'[i]
        int j = rs;
        for (; j + 4 <= re; j += 4) {
            int2 e0 = ep[j], e1 = ep[j + 1], e2 = ep[j + 2], e3 = ep[j + 3];
            unsigned v0 = xw[(size_t)e0.x * 64 + lane];
            unsigned v1 = xw[(size_t)e1.x * 64 + lane];
            unsigned v2 = xw[(size_t)e2.x * 64 + lane];
            unsigned v3 = xw[(size_t)e3.x * 64 + lane];
            float c0 = __int_as_float(e0.y), c1 = __int_as_float(e1.y);
            float c2 = __int_as_float(e2.y), c3 = __int_as_float(e3.y);
            float2 f0 = bf2_unpack(v0), f1 = bf2_unpack(v1);
            float2 f2 = bf2_unpack(v2), f3 = bf2_unpack(v3);
            acc0 += c0 * f0.x + c1 * f1.x + c2 * f2.x + c3 * f3.x;
            acc1 += c0 * f0.y + c1 * f1.y + c2 * f2.y + c3 * f3.y;
        }
        for (; j < re; j++) {
            int2 e = ep[j];
            float c = __int_as_float(e.y);
            float2 f = bf2_unpack(xw[(size_t)e.x * 64 + lane]);
            acc0 += c * f.x;
            acc1 += c * f.y;
        }
        acc0 = acc0 * di + b0;
        acc1 = acc1 * di + b1;
        *(float2*)&h[(size_t)i * 128 + 2 * lane] = make_float2(acc0, acc1);
        s0 += acc0; s1 += acc1; q0 += acc0 * acc0; q1 += acc1 * acc1;
    }

    redS[wave * 128 + 2 * lane] = s0;
    redS[wave * 128 + 2 * lane + 1] = s1;
    redQ[wave * 128 + 2 * lane] = q0;
    redQ[wave * 128 + 2 * lane + 1] = q1;
    __syncthreads();
    if (threadIdx.x < 128) {
        int f = threadIdx.x;
        float ts = redS[f] + redS[128 + f] + redS[256 + f] + redS[384 + f];
        float tq = redQ[f] + redQ[128 + f] + redQ[256 + f] + redQ[384 + f];
        atomicAdd(&bn_sum[f], ts);
        atomicAdd(&bn_sq[f], tq);
    }
}

// ---------- BN finalize ----------
__global__ void k_bnfin(const float* __restrict__ bn_sum, const float* __restrict__ bn_sq,
                        const float* __restrict__ gamma, const float* __restrict__ beta,
                        float* __restrict__ scale, float* __restrict__ shift, int N) {
    int f = threadIdx.x;
    float inv = 1.0f / (float)N;
    float m = bn_sum[f] * inv;
    float v = bn_sq[f] * inv - m * m;
    float sc = gamma[f] * rsqrtf(v + 1e-5f);
    scale[f] = sc;
    shift[f] = beta[f] - m * sc;
}

// ---------- aggregation (40-wide, bf16 gather) + bias + log_softmax ----------
__global__ __launch_bounds__(256) void k_agg40(
    const unsigned* __restrict__ xw, const int* __restrict__ rowptr,
    const int2* __restrict__ ep, const float* __restrict__ dinv,
    const float* __restrict__ bias, float* __restrict__ out, int N)
{
    const int lane = threadIdx.x & 63;
    const int wave = threadIdx.x >> 6;
    const int half = lane >> 5;
    const int col = lane & 31;
    const bool act = col < 20;
    const int base = blockIdx.x * 64 + wave * 16;
    if (base >= N) return;
    const int cc = act ? col : 0;
    const float b0 = act ? bias[2 * col] : 0.f;
    const float b1 = act ? bias[2 * col + 1] : 0.f;

    for (int n = 0; n < 16; n += 2) {
        const int i = base + n + half;
        const bool valid = i < N;
        const int ic = valid ? i : 0;
        const int rs = rowptr[ic];
        int re = rowptr[ic + 1];
        re = valid ? re : rs;
        const float di = dinv[ic];
        float2 sv = bf2_unpack(xw[(size_t)ic * 20 + cc]);
        float acc0 = sv.x, acc1 = sv.y;  // self-loop message
        int j = rs;
        for (; j + 4 <= re; j += 4) {
            int2 e0 = ep[j], e1 = ep[j + 1], e2 = ep[j + 2], e3 = ep[j + 3];
            unsigned v0 = xw[(size_t)e0.x * 20 + cc];
            unsigned v1 = xw[(size_t)e1.x * 20 + cc];
            unsigned v2 = xw[(size_t)e2.x * 20 + cc];
            unsigned v3 = xw[(size_t)e3.x * 20 + cc];
            float c0 = __int_as_float(e0.y), c1 = __int_as_float(e1.y);
            float c2 = __int_as_float(e2.y), c3 = __int_as_float(e3.y);
            float2 f0 = bf2_unpack(v0), f1 = bf2_unpack(v1);
            float2 f2 = bf2_unpack(v2), f3 = bf2_unpack(v3);
            acc0 += c0 * f0.x + c1 * f1.x + c2 * f2.x + c3 * f3.x;
            acc1 += c0 * f0.y + c1 * f1.y + c2 * f2.y + c3 * f3.y;
        }
        for (; j < re; j++) {
            int2 e = ep[j];
            float c = __int_as_float(e.y);
            float2 f = bf2_unpack(xw[(size_t)e.x * 20 + cc]);
            acc0 += c * f.x;
            acc1 += c * f.y;
        }
        acc0 = acc0 * di + b0;
        acc1 = acc1 * di + b1;

        float m = act ? fmaxf(acc0, acc1) : -1e30f;
#pragma unroll
        for (int off = 16; off; off >>= 1) m = fmaxf(m, __shfl_xor(m, off));
        float ex = act ? (expf(acc0 - m) + expf(acc1 - m)) : 0.f;
#pragma unroll
        for (int off = 16; off; off >>= 1) ex += __shfl_xor(ex, off);
        float ls = logf(ex);
        if (act && valid)
            *(float2*)&out[(size_t)i * 40 + 2 * col] = make_float2(acc0 - m - ls, acc1 - m - ls);
    }
}

// ---------------------------------------------------------------------------
extern "C" void kernel_launch(void* const* d_in, const int* in_sizes, int n_in,
                              void* d_out, int out_size, void* d_ws, size_t ws_size,
                              hipStream_t stream) {
    const float* x   = (const float*)d_in[0];
    const unsigned* ei = (const unsigned*)d_in[1];
    const float* ew  = (const float*)d_in[2];
    const float* W0  = (const float*)d_in[3];
    const float* b0  = (const float*)d_in[4];
    const float* g0  = (const float*)d_in[5];
    const float* be0 = (const float*)d_in[6];
    const float* W1  = (const float*)d_in[7];
    const float* b1  = (const float*)d_in[8];
    const float* g1  = (const float*)d_in[9];
    const float* be1 = (const float*)d_in[10];
    const float* W2  = (const float*)d_in[11];
    const float* b2  = (const float*)d_in[12];

    const int N = in_sizes[0] / 128;
    const int E = in_sizes[2];
    if (N <= 0 || E <= 0) return;
    const int NB = (N + 255) >> 8;                 // buckets (<=512)
    const int nchunks = (E + CHUNK - 1) / CHUNK;   // partition chunks

    char* ws = (char*)d_ws;
    size_t off = 0;
    auto carve = [&](size_t bytes) {
        char* p = ws + off;
        off += (bytes + 511) & ~((size_t)511);
        return p;
    };
    float*    F       = (float*)carve((size_t)N * 128 * 4);    // fp32 h buffer
    unsigned* P       = (unsigned*)carve((size_t)N * 64 * 4);  // packed bf162 xw'
    int2*     ep      = (int2*)carve((size_t)E * 8);           // final CSR (src, ew)
    int2*     staging = (int2*)carve((size_t)E * 8);           // bucket-ordered edges
    int*      chist   = (int*)carve((size_t)nchunks * 512 * 4);
    int*      rowptr  = (int*)carve((size_t)(N + 1) * 4);
    float*    dinv    = (float*)carve((size_t)N * 4);
    int*      bhist   = (int*)carve(513 * 4);
    int*      bstart  = (int*)carve(513 * 4);
    int*      bcur    = (int*)carve(513 * 4);
    float*    bn      = (float*)carve(512 * 4);
    int*      flag    = (int*)carve(64);

    hipMemsetAsync(bhist, 0, 513 * 4, stream);
    hipMemsetAsync(flag, 0, 4, stream);

    int nsample = E < 4096 ? E : 4096;
    k_detect<<<(nsample + 255) / 256, 256, 0, stream>>>(ei, nsample, flag);
    int pgrid = nchunks < 1024 ? nchunks : 1024;
    k_bhist<<<pgrid, 256, 0, stream>>>(ei, bhist, chist, flag, E, NB, nchunks);
    k_bscan<<<1, 512, 0, stream>>>(bhist, bstart, bcur, NB);
    k_part<<<pgrid, 256, 0, stream>>>(ei, ew, chist, bcur, staging, flag, E, NB, nchunks);
    k_bucket<<<NB, 256, 0, stream>>>(bstart, staging, rowptr, dinv, ep, N, NB);

    const int gemm_grid = 768;
    const int agg_grid = (N + 63) / 64;

    // ---- layer 0 ----
    k_gemm<128, 64, false><<<gemm_grid, 256, 0, stream>>>(x, W0, nullptr, nullptr, dinv, P, N);
    hipMemsetAsync(bn, 0, 1024, stream);
    k_agg128<<<agg_grid, 256, 0, stream>>>(P, rowptr, ep, dinv, b0, F, bn, bn + 128, N);
    k_bnfin<<<1, 128, 0, stream>>>(bn, bn + 128, g0, be0, bn + 256, bn + 384, N);

    // ---- layer 1 ----
    k_gemm<128, 64, true><<<gemm_grid, 256, 0, stream>>>(F, W1, bn + 256, bn + 384, dinv, P, N);
    hipMemsetAsync(bn, 0, 1024, stream);
    k_agg128<<<agg_grid, 256, 0, stream>>>(P, rowptr, ep, dinv, b1, F, bn, bn + 128, N);
    k_bnfin<<<1, 128, 0, stream>>>(bn, bn + 128, g1, be1, bn + 256, bn + 384, N);

    // ---- layer 2 ----
    k_gemm<40, 128, true><<<gemm_grid, 256, 0, stream>>>(F, W2, bn + 256, bn + 384, dinv, P, N);
    k_agg40<<<agg_grid, 256, 0, stream>>>(P, rowptr, ep, dinv, b2, (float*)d_out, N);
}